// Round 6
// baseline (304.502 us; speedup 1.0000x reference)
//
#include <hip/hip_runtime.h>
#include <math.h>

typedef short  short8  __attribute__((ext_vector_type(8)));
typedef float  f32x4   __attribute__((ext_vector_type(4)));

#define BATCH 32768
#define DIN   256
#define DOUT  512
#define BM    128
#define BN    64

// round-to-nearest-even fp32 -> bf16 bits
__device__ __forceinline__ short f2bf(float v) {
    unsigned u = __float_as_uint(v);
    u += 0x7fffu + ((u >> 16) & 1u);
    return (short)(u >> 16);
}

// direct global->LDS DMA, 16B per lane, zero VGPR cost for the payload
__device__ __forceinline__ void gload_lds16(const void* g, void* l) {
    __builtin_amdgcn_global_load_lds(
        (const __attribute__((address_space(1))) unsigned int*)g,
        (__attribute__((address_space(3))) unsigned int*)l, 16, 0, 0);
}

// ---------------------------------------------------------------------------
// r12 prepass: SPK flag scan ONLY (64 MB pure read ~= 10.5us at stream BW).
// All fp32->bf16 conversion work moved into the main kernel (in-register,
// VALU was 7% idle there). Workspace shrinks to just flags[256].
// ---------------------------------------------------------------------------
__global__ __launch_bounds__(256) void scan_kernel(
    const float* __restrict__ SPK, int* __restrict__ flags)
{
    const int b   = blockIdx.x;      // 0..2047, 16 SPK rows each
    const int tid = threadIdx.x;
    unsigned bits = 0;
    const f32x4* p = (const f32x4*)SPK + (size_t)b * 2048;
#pragma unroll
    for (int j = 0; j < 8; j++) {
        f32x4 v = p[tid + j * 256];
        bits |= __float_as_uint(v[0]) | __float_as_uint(v[1])
              | __float_as_uint(v[2]) | __float_as_uint(v[3]);
    }
    if (__any(bits != 0) && (tid & 63) == 0)
        atomicOr(&flags[b >> 3], 1);
}

// ---------------------------------------------------------------------------
// Main kernel, r12: X and Wd staged DIRECTLY as f32 via global_load_lds,
// f2bf conversion after ds_read (phase-2 pattern, proven). Deletes the X
// round-trip (prepass X 32R + X2 16W + main X2 16R) -> prepass collapses to
// scan-only. r10==r11 showed stage-latency exposure is negligible at 3
// resident blocks, so this uses the simpler SERIAL single-buffer loop:
// 4 chunks of K=64, A f32 [128][64] (32KB) + B f32 [64][64] (16KB) = 48KB.
//
// Swizzle (rule #21, both-sides involution at 16B granularity): LDS slot p
// of row r holds global slot p ^ ((r&7)<<4); DMA source pre-applies it,
// ds_read re-applies it. 256B rows, XOR bits 4-6 -> b128 reads stay 16B-
// aligned and in-row.
//
// Phase 2 reads Wr as f32 and converts in-register too (cold path).
// All conversions bit-identical (same f2bf RNE) -> absmax must not move.
// ---------------------------------------------------------------------------
__global__ __launch_bounds__(256, 3) void spike_rnn_lif_kernel(
    const float* __restrict__ X,    // f32 [B, 256]
    const float* __restrict__ MEM,  // [B, 512]
    const float* __restrict__ SPK,  // [B, 512]
    const float* __restrict__ Wd,   // f32 [512, 256]
    const float* __restrict__ bd,   // [512]
    const float* __restrict__ Wr,   // f32 [512, 512]
    const float* __restrict__ br,   // [512]
    const float* __restrict__ tau,  // [512]
    const int*   __restrict__ flags,// [256]
    float* __restrict__ out)        // [2, B, 512]
{
    // A f32 [128][64] @0 (32KB, 256B rows) | B f32 [64][64] @32768 (16KB)
    __shared__ __align__(16) char smem[49152];
    float* sT = (float*)smem;                    // epilogue overlay (17.4 KB)

    const int tid  = threadIdx.x;
    const int lane = tid & 63;
    const int w    = tid >> 6;
    const int wm   = w & 1;
    const int wn   = w >> 1;

    // XCD swizzle decode (bijective): L = ((bm/8)*8 + bn)*8 + bm%8
    const int L    = blockIdx.x;
    const int bm   = ((L >> 6) << 3) + (L & 7);
    const int bn   = (L >> 3) & 7;
    const int m0   = bm * BM;
    const int n0   = bn * BN;
    const int col  = lane & 15;
    const int quad = lane >> 4;

    const bool has_spk = (flags[bm] != 0);

    // Stage K-chunk c0 (64 f32 cols = 256B/row). A: 32 segs of 1KB (4 rows
    // x 256B each); B: 16 segs. 12 DMA/wave -> same in-flight depth as r10.
#define STAGE(c0)                                                             \
    do {                                                                      \
        _Pragma("unroll")                                                     \
        for (int i = 0; i < 8; i++) {                                         \
            int seg = w * 8 + i;                                              \
            int r   = seg * 4 + (lane >> 4);                                  \
            const char* src = (const char*)X + (size_t)(m0 + r) * 1024        \
                + (c0) * 256 + (((lane & 15) * 16) ^ ((r & 7) << 4));         \
            gload_lds16(src, smem + seg * 1024);                              \
        }                                                                     \
        _Pragma("unroll")                                                     \
        for (int i = 0; i < 4; i++) {                                         \
            int seg = w * 4 + i;                                              \
            int r   = seg * 4 + (lane >> 4);                                  \
            const char* src = (const char*)Wd + (size_t)(n0 + r) * 1024       \
                + (c0) * 256 + (((lane & 15) * 16) ^ ((r & 7) << 4));         \
            gload_lds16(src, smem + 32768 + seg * 1024);                      \
        }                                                                     \
    } while (0)

    // ---- Prologue: chunk-0 DMA first, then MEM epilogue prefetch ----
    STAGE(0);

    const int c4   = tid & 15;
    const int ncol = n0 + c4 * 4;
    f32x4 mv0[4], mv1[4];
#pragma unroll
    for (int it = 0; it < 4; it++) {
        int r2 = (tid + it * 256) >> 4;
        mv0[it] = __builtin_nontemporal_load(
                      (const f32x4*)(MEM + (size_t)(m0 + r2) * DOUT + ncol));
        mv1[it] = __builtin_nontemporal_load(
                      (const f32x4*)(MEM + (size_t)(m0 + 64 + r2) * DOUT + ncol));
    }

    f32x4 acc[4][2];
#pragma unroll
    for (int i = 0; i < 4; i++)
#pragma unroll
        for (int j = 0; j < 2; j++)
            acc[i][j] = (f32x4){0.f, 0.f, 0.f, 0.f};

    const int swz  = (col & 7) << 4;   // row&7 == col&7 for all frag rows
    const int arow = wm * 64 + col;
    const int brow = wn * 32 + col;

    // Read 8 f32 (two swizzled 16B slots), convert to bf16x8.
#define PACK8(base, o0, dst)                                                  \
    do {                                                                      \
        f32x4 lo_ = *(const f32x4*)((base) + (((o0)     ) ^ swz));            \
        f32x4 hi_ = *(const f32x4*)((base) + (((o0) + 16) ^ swz));            \
        dst = (short8){f2bf(lo_[0]), f2bf(lo_[1]), f2bf(lo_[2]), f2bf(lo_[3]),\
                       f2bf(hi_[0]), f2bf(hi_[1]), f2bf(hi_[2]), f2bf(hi_[3])};\
    } while (0)

#define DSLOAD(kk, aa, bb)                                                    \
    do {                                                                      \
        int o0 = (kk) * 128 + quad * 32;                                      \
        _Pragma("unroll")                                                     \
        for (int t = 0; t < 4; t++)                                           \
            PACK8(smem + (size_t)(arow + t * 16) * 256, o0, aa[t]);           \
        _Pragma("unroll")                                                     \
        for (int t = 0; t < 2; t++)                                           \
            PACK8(smem + 32768 + (size_t)(brow + t * 16) * 256, o0, bb[t]);   \
    } while (0)

#define MFMA_AB(aa, bb)                                                       \
    do {                                                                      \
        _Pragma("unroll")                                                     \
        for (int i = 0; i < 4; i++)                                           \
            _Pragma("unroll")                                                 \
            for (int j = 0; j < 2; j++)                                       \
                acc[i][j] = __builtin_amdgcn_mfma_f32_16x16x32_bf16(          \
                    aa[i], bb[j], acc[i][j], 0, 0, 0);                        \
    } while (0)

    short8 a0[4], b0[2], a1[4], b1[2];

    __syncthreads();                        // chunk 0 + MEM prefetch landed
#pragma unroll
    for (int c = 0; c < 4; c++) {
        DSLOAD(0, a0, b0);
        DSLOAD(1, a1, b1);
        MFMA_AB(a0, b0);
        MFMA_AB(a1, b1);
        if (c < 3) {
            __syncthreads();                // all waves done reading chunk c
            STAGE(c + 1);
            __syncthreads();                // vmcnt(0)+barrier: chunk c+1 in
        }
    }
#undef DSLOAD
#undef STAGE

    // ---- Phase 2: recurrent GEMM, K=512 — only when spikes exist ----
    if (has_spk) {
        const float* Abase = SPK + (size_t)(m0 + wm * 64 + col) * DOUT + quad * 8;
        const float* Bbase = Wr  + (size_t)(n0 + wn * 32 + col) * DOUT + quad * 8;
#pragma unroll 4
        for (int ks = 0; ks < 16; ks++) {
            int k = ks * 32;
            short8 a[4], b[2];
#pragma unroll
            for (int t = 0; t < 4; t++) {
                const float* ap = Abase + (size_t)t * 16 * DOUT + k;
                f32x4 lo = *(const f32x4*)ap;
                f32x4 hi = *(const f32x4*)(ap + 4);
                a[t] = (short8){f2bf(lo[0]), f2bf(lo[1]), f2bf(lo[2]), f2bf(lo[3]),
                                f2bf(hi[0]), f2bf(hi[1]), f2bf(hi[2]), f2bf(hi[3])};
            }
#pragma unroll
            for (int t = 0; t < 2; t++) {
                const float* bp = Bbase + (size_t)t * 16 * DOUT + k;
                f32x4 lo = *(const f32x4*)bp;
                f32x4 hi = *(const f32x4*)(bp + 4);
                b[t] = (short8){f2bf(lo[0]), f2bf(lo[1]), f2bf(lo[2]), f2bf(lo[3]),
                                f2bf(hi[0]), f2bf(hi[1]), f2bf(hi[2]), f2bf(hi[3])};
            }
            MFMA_AB(a, b);
        }
    }
#undef MFMA_AB
#undef PACK8

    float al[4], oma[4], bs[4];
#pragma unroll
    for (int q = 0; q < 4; q++) {
        al[q]  = expf(-1.0f / tau[ncol + q]);
        oma[q] = 1.0f - al[q];
        bs[q]  = bd[ncol + q] + br[ncol + q];
    }

    __syncthreads();   // single staging buffer: readers done before sT overlay

#pragma unroll
    for (int c = 0; c < 2; c++) {
        if (c) __syncthreads();
        if (wm == c) {
            // C/D layout (verified): col = lane&15, row = quad*4 + reg
#pragma unroll
            for (int j = 0; j < 2; j++)
#pragma unroll
                for (int i = 0; i < 4; i++)
#pragma unroll
                    for (int rr = 0; rr < 4; rr++)
                        sT[(i * 16 + quad * 4 + rr) * 68 + wn * 32 + j * 16 + col]
                            = acc[i][j][rr];
        }
        __syncthreads();
#pragma unroll
        for (int it = 0; it < 4; it++) {
            int p   = tid + it * 256;
            int r2  = p >> 4;
            int row = m0 + c * 64 + r2;
            f32x4 d  = *(const f32x4*)(sT + r2 * 68 + c4 * 4);
            f32x4 mv = c ? mv1[it] : mv0[it];
            f32x4 sv = has_spk ? *(const f32x4*)(SPK + (size_t)row * DOUT + ncol)
                               : (f32x4){0.f, 0.f, 0.f, 0.f};
            f32x4 mn, sp;
#pragma unroll
            for (int q = 0; q < 4; q++) {
                mn[q] = mv[q] * al[q] + oma[q] * (d[q] + bs[q]) - 0.5f * sv[q];
                sp[q] = (mn[q] - 0.5f > 0.0f) ? 1.0f : 0.0f;
            }
            __builtin_nontemporal_store(mn,
                (f32x4*)(out + (size_t)row * DOUT + ncol));
            __builtin_nontemporal_store(sp,
                (f32x4*)(out + (size_t)BATCH * DOUT + (size_t)row * DOUT + ncol));
        }
    }
}

extern "C" void kernel_launch(void* const* d_in, const int* in_sizes, int n_in,
                              void* d_out, int out_size, void* d_ws, size_t ws_size,
                              hipStream_t stream) {
    const float* X   = (const float*)d_in[0];
    const float* MEM = (const float*)d_in[1];
    const float* SPK = (const float*)d_in[2];
    const float* Wd  = (const float*)d_in[3];
    const float* bd  = (const float*)d_in[4];
    const float* Wr  = (const float*)d_in[5];
    const float* br  = (const float*)d_in[6];
    const float* tau = (const float*)d_in[7];

    int* flags = (int*)d_ws;

    hipMemsetAsync(flags, 0, 256 * sizeof(int), stream);   // graph-capture-safe
    scan_kernel<<<2048, 256, 0, stream>>>(SPK, flags);

    spike_rnn_lif_kernel<<<2048, 256, 0, stream>>>(X, MEM, SPK, Wd, bd, Wr, br,
                                                   tau, flags, (float*)d_out);
}

// Round 7
// 281.770 us; speedup vs baseline: 1.0807x; 1.0807x over previous
//
#include <hip/hip_runtime.h>
#include <math.h>

typedef short  short8  __attribute__((ext_vector_type(8)));
typedef short  short4v __attribute__((ext_vector_type(4)));
typedef float  f32x4   __attribute__((ext_vector_type(4)));

#define BATCH 32768
#define DIN   256
#define DOUT  512
#define BM    128
#define BN    64

// ws layout (bytes)
#define WS_FLAGS 0
#define WS_WD2   4096
#define WS_WR2   (4096 + 262144)
#define WS_X2    (266240 + 524288)

// round-to-nearest-even fp32 -> bf16 bits
__device__ __forceinline__ short f2bf(float v) {
    unsigned u = __float_as_uint(v);
    u += 0x7fffu + ((u >> 16) & 1u);
    return (short)(u >> 16);
}

// direct global->LDS DMA, 16B per lane, zero VGPR cost for the payload
__device__ __forceinline__ void gload_lds16(const void* g, void* l) {
    __builtin_amdgcn_global_load_lds(
        (const __attribute__((address_space(1))) unsigned int*)g,
        (__attribute__((address_space(3))) unsigned int*)l, 16, 0, 0);
}

// ---------------------------------------------------------------------------
// Fused pre-pass (r4 verbatim — measured at 94% of its 119MB stream roofline):
//   A) SPK flag scan (64 MB)  B) X fp32->bf16 (48 MB)  C) W fp32->bf16 (7 MB)
// r6 lesson: do NOT move conversions into main (2x LDS traffic, cvt on the
// DSLOAD->MFMA critical path, register spills: WRITE_SIZE +65MB).
// ---------------------------------------------------------------------------
__global__ __launch_bounds__(256) void prepass_kernel(
    const float* __restrict__ SPK, const float* __restrict__ X,
    const float* __restrict__ Wd,  const float* __restrict__ Wr,
    int* __restrict__ flags, short* __restrict__ X2,
    short* __restrict__ Wd2, short* __restrict__ Wr2)
{
    const int b   = blockIdx.x;      // 0..2047
    const int tid = threadIdx.x;

    {
        unsigned bits = 0;
        const f32x4* p = (const f32x4*)SPK + (size_t)b * 2048;
#pragma unroll
        for (int j = 0; j < 8; j++) {
            f32x4 v = p[tid + j * 256];
            bits |= __float_as_uint(v[0]) | __float_as_uint(v[1])
                  | __float_as_uint(v[2]) | __float_as_uint(v[3]);
        }
        if (__any(bits != 0) && (tid & 63) == 0)
            atomicOr(&flags[b >> 3], 1);
    }

    {
        const f32x4* src = (const f32x4*)X + (size_t)b * 1024;
        short4v*     dst = (short4v*)X2   + (size_t)b * 1024;
#pragma unroll
        for (int j = 0; j < 4; j++) {
            f32x4 v = src[tid + j * 256];
            dst[tid + j * 256] = (short4v){f2bf(v[0]), f2bf(v[1]),
                                           f2bf(v[2]), f2bf(v[3])};
        }
    }

    {
        int idx = b * 256 + tid;
        if (idx < 32768) {
            f32x4 v = ((const f32x4*)Wd)[idx];
            ((short4v*)Wd2)[idx] = (short4v){f2bf(v[0]), f2bf(v[1]),
                                             f2bf(v[2]), f2bf(v[3])};
        } else if (idx < 98304) {
            int k = idx - 32768;
            f32x4 v = ((const f32x4*)Wr)[k];
            ((short4v*)Wr2)[k] = (short4v){f2bf(v[0]), f2bf(v[1]),
                                           f2bf(v[2]), f2bf(v[3])};
        }
    }
}

// ---------------------------------------------------------------------------
// Main kernel, r13: r4 structure at 4 blocks/CU.
//
// Evidence: r4 main ~47us = 3.7 TB/s aggregate on 173MB; per-CU block wall
// time ~42k cyc vs ~3k critical path -> blocks queue on HBM service, and
// 3 phase-correlated resident blocks give bursty R-then-W per CU. Earlier
// occupancy pushes (r1/r3) failed because residency was paid with in-flight
// depth (registers were the token). global_load_lds decoupled that: depth
// lives in the DMA queue. So buy residency: LDS 48->24KB (K=64 chunks x4,
// serial single buffer; r10==r11 proved stage-exposure is covered), single
// frag set a0/b0 (-24 regs, ds latency covered by 16 waves/CU), and
// __launch_bounds__(256,4). Peak unified regs ~110 <= 128 cap -> no spill
// (watch WRITE_SIZE: +MBs there = spill = falsified).
// Prepass / swizzle involution / epilogue / nt stores: r4 verbatim.
// ---------------------------------------------------------------------------
__global__ __launch_bounds__(256, 4) void spike_rnn_lif_kernel(
    const short* __restrict__ X2,   // bf16 [B, 256]
    const float* __restrict__ MEM,  // [B, 512]
    const float* __restrict__ SPK,  // [B, 512]
    const short* __restrict__ Wd2,  // bf16 [512, 256]
    const float* __restrict__ bd,   // [512]
    const short* __restrict__ Wr2,  // bf16 [512, 512]
    const float* __restrict__ br,   // [512]
    const float* __restrict__ tau,  // [512]
    const int*   __restrict__ flags,// [256]
    float* __restrict__ out)        // [2, B, 512]
{
    // A bf16 [128][64] @0 (16KB, 128B rows) | B bf16 [64][64] @16384 (8KB)
    __shared__ __align__(16) char smem[24576];
    float* sT = (float*)smem;                    // epilogue overlay (17.4 KB)

    const int tid  = threadIdx.x;
    const int lane = tid & 63;
    const int w    = tid >> 6;
    const int wm   = w & 1;
    const int wn   = w >> 1;

    // XCD swizzle decode (bijective): L = ((bm/8)*8 + bn)*8 + bm%8
    const int L    = blockIdx.x;
    const int bm   = ((L >> 6) << 3) + (L & 7);
    const int bn   = (L >> 3) & 7;
    const int m0   = bm * BM;
    const int n0   = bn * BN;
    const int col  = lane & 15;
    const int quad = lane >> 4;

    const bool has_spk = (flags[bm] != 0);

    // Stage K-chunk c0 (64 bf16 cols = 128B/row). A: 16 segs of 1KB (8 rows
    // x 128B); B: 8 segs. 6 DMA/wave x 16 waves/CU = 96KB/CU in flight.
    // Swizzle: source slot ^ ((r&7)<<4), linear LDS dest (involution; read
    // re-applies it). r11-verified macros.
#define STAGE(c0)                                                             \
    do {                                                                      \
        _Pragma("unroll")                                                     \
        for (int i = 0; i < 4; i++) {                                         \
            int seg = w * 4 + i;                                              \
            int r   = seg * 8 + (lane >> 3);                                  \
            const char* src = (const char*)X2 + (size_t)(m0 + r) * 512        \
                + (c0) * 128 + (((lane & 7) * 16) ^ ((r & 7) << 4));          \
            gload_lds16(src, smem + seg * 1024);                              \
        }                                                                     \
        _Pragma("unroll")                                                     \
        for (int i = 0; i < 2; i++) {                                         \
            int seg = w * 2 + i;                                              \
            int r   = seg * 8 + (lane >> 3);                                  \
            const char* src = (const char*)Wd2 + (size_t)(n0 + r) * 512       \
                + (c0) * 128 + (((lane & 7) * 16) ^ ((r & 7) << 4));          \
            gload_lds16(src, smem + 16384 + seg * 1024);                      \
        }                                                                     \
    } while (0)

    // ---- Prologue: chunk-0 DMA first, then MEM epilogue prefetch ----
    STAGE(0);

    const int c4   = tid & 15;
    const int ncol = n0 + c4 * 4;
    f32x4 mv0[4], mv1[4];
#pragma unroll
    for (int it = 0; it < 4; it++) {
        int r2 = (tid + it * 256) >> 4;
        mv0[it] = __builtin_nontemporal_load(
                      (const f32x4*)(MEM + (size_t)(m0 + r2) * DOUT + ncol));
        mv1[it] = __builtin_nontemporal_load(
                      (const f32x4*)(MEM + (size_t)(m0 + 64 + r2) * DOUT + ncol));
    }

    f32x4 acc[4][2];
#pragma unroll
    for (int i = 0; i < 4; i++)
#pragma unroll
        for (int j = 0; j < 2; j++)
            acc[i][j] = (f32x4){0.f, 0.f, 0.f, 0.f};

    const int swz  = (col & 7) << 4;
    const int arow = wm * 64 + col;
    const int brow = wn * 32 + col;

#define DSLOAD(kk, aa, bb)                                                    \
    do {                                                                      \
        int ko = (quad * 16 + (kk) * 64) ^ swz;                               \
        _Pragma("unroll")                                                     \
        for (int t = 0; t < 4; t++)                                           \
            aa[t] = *(const short8*)(smem + (arow + t * 16) * 128 + ko);      \
        _Pragma("unroll")                                                     \
        for (int t = 0; t < 2; t++)                                           \
            bb[t] = *(const short8*)(smem + 16384 + (brow + t * 16) * 128 + ko); \
    } while (0)

#define MFMA_AB(aa, bb)                                                       \
    do {                                                                      \
        _Pragma("unroll")                                                     \
        for (int i = 0; i < 4; i++)                                           \
            _Pragma("unroll")                                                 \
            for (int j = 0; j < 2; j++)                                       \
                acc[i][j] = __builtin_amdgcn_mfma_f32_16x16x32_bf16(          \
                    aa[i], bb[j], acc[i][j], 0, 0, 0);                        \
    } while (0)

    short8 a0[4], b0[2];

    __syncthreads();                        // chunk 0 + MEM prefetch landed
#pragma unroll
    for (int c = 0; c < 4; c++) {
        DSLOAD(0, a0, b0);
        MFMA_AB(a0, b0);
        DSLOAD(1, a0, b0);
        MFMA_AB(a0, b0);
        if (c < 3) {
            __syncthreads();                // all waves done reading chunk c
            STAGE(c + 1);
            __syncthreads();                // vmcnt(0)+barrier: chunk c+1 in
        }
    }
#undef DSLOAD
#undef STAGE

    // ---- Phase 2: recurrent GEMM, K=512 — only when spikes exist ----
    if (has_spk) {
        const float* Abase = SPK + (size_t)(m0 + wm * 64 + col) * DOUT + quad * 8;
        const short* Bbase = Wr2 + (size_t)(n0 + wn * 32 + col) * DOUT + quad * 8;
#pragma unroll 4
        for (int ks = 0; ks < 16; ks++) {
            int k = ks * 32;
            short8 a[4], b[2];
#pragma unroll
            for (int t = 0; t < 4; t++) {
                const float* ap = Abase + (size_t)t * 16 * DOUT + k;
                f32x4 lo = *(const f32x4*)ap;
                f32x4 hi = *(const f32x4*)(ap + 4);
                a[t] = (short8){f2bf(lo[0]), f2bf(lo[1]), f2bf(lo[2]), f2bf(lo[3]),
                                f2bf(hi[0]), f2bf(hi[1]), f2bf(hi[2]), f2bf(hi[3])};
            }
#pragma unroll
            for (int t = 0; t < 2; t++)
                b[t] = *(const short8*)(Bbase + (size_t)t * 16 * DOUT + k);
            MFMA_AB(a, b);
        }
    }
#undef MFMA_AB

    float al[4], oma[4], bs[4];
#pragma unroll
    for (int q = 0; q < 4; q++) {
        al[q]  = expf(-1.0f / tau[ncol + q]);
        oma[q] = 1.0f - al[q];
        bs[q]  = bd[ncol + q] + br[ncol + q];
    }

    __syncthreads();   // single staging buffer: GEMM readers done before sT

#pragma unroll
    for (int c = 0; c < 2; c++) {
        if (c) __syncthreads();
        if (wm == c) {
            // C/D layout (verified): col = lane&15, row = quad*4 + reg
#pragma unroll
            for (int j = 0; j < 2; j++)
#pragma unroll
                for (int i = 0; i < 4; i++)
#pragma unroll
                    for (int rr = 0; rr < 4; rr++)
                        sT[(i * 16 + quad * 4 + rr) * 68 + wn * 32 + j * 16 + col]
                            = acc[i][j][rr];
        }
        __syncthreads();
#pragma unroll
        for (int it = 0; it < 4; it++) {
            int p   = tid + it * 256;
            int r2  = p >> 4;
            int row = m0 + c * 64 + r2;
            f32x4 d  = *(const f32x4*)(sT + r2 * 68 + c4 * 4);
            f32x4 mv = c ? mv1[it] : mv0[it];
            f32x4 sv = has_spk ? *(const f32x4*)(SPK + (size_t)row * DOUT + ncol)
                               : (f32x4){0.f, 0.f, 0.f, 0.f};
            f32x4 mn, sp;
#pragma unroll
            for (int q = 0; q < 4; q++) {
                mn[q] = mv[q] * al[q] + oma[q] * (d[q] + bs[q]) - 0.5f * sv[q];
                sp[q] = (mn[q] - 0.5f > 0.0f) ? 1.0f : 0.0f;
            }
            __builtin_nontemporal_store(mn,
                (f32x4*)(out + (size_t)row * DOUT + ncol));
            __builtin_nontemporal_store(sp,
                (f32x4*)(out + (size_t)BATCH * DOUT + (size_t)row * DOUT + ncol));
        }
    }
}

extern "C" void kernel_launch(void* const* d_in, const int* in_sizes, int n_in,
                              void* d_out, int out_size, void* d_ws, size_t ws_size,
                              hipStream_t stream) {
    const float* X   = (const float*)d_in[0];
    const float* MEM = (const float*)d_in[1];
    const float* SPK = (const float*)d_in[2];
    const float* Wd  = (const float*)d_in[3];
    const float* bd  = (const float*)d_in[4];
    const float* Wr  = (const float*)d_in[5];
    const float* br  = (const float*)d_in[6];
    const float* tau = (const float*)d_in[7];

    char*  ws    = (char*)d_ws;
    int*   flags = (int*)  (ws + WS_FLAGS);
    short* Wd2   = (short*)(ws + WS_WD2);
    short* Wr2   = (short*)(ws + WS_WR2);
    short* X2    = (short*)(ws + WS_X2);

    hipMemsetAsync(flags, 0, 256 * sizeof(int), stream);   // graph-capture-safe
    prepass_kernel<<<2048, 256, 0, stream>>>(SPK, X, Wd, Wr, flags, X2, Wd2, Wr2);

    spike_rnn_lif_kernel<<<2048, 256, 0, stream>>>(X2, MEM, SPK, Wd2, bd, Wr2, br,
                                                   tau, flags, (float*)d_out);
}

// Round 8
// 272.381 us; speedup vs baseline: 1.1179x; 1.0345x over previous
//
#include <hip/hip_runtime.h>
#include <math.h>

typedef short  short8  __attribute__((ext_vector_type(8)));
typedef short  short4v __attribute__((ext_vector_type(4)));
typedef float  f32x4   __attribute__((ext_vector_type(4)));

#define BATCH 32768
#define DIN   256
#define DOUT  512
#define BM    128
#define BN    64

// ws layout (bytes)
#define WS_FLAGS 0
#define WS_WD2   4096
#define WS_WR2   (4096 + 262144)
#define WS_X2    (266240 + 524288)

// round-to-nearest-even fp32 -> bf16 bits
__device__ __forceinline__ short f2bf(float v) {
    unsigned u = __float_as_uint(v);
    u += 0x7fffu + ((u >> 16) & 1u);
    return (short)(u >> 16);
}

// direct global->LDS DMA, 16B per lane, zero VGPR cost for the payload
__device__ __forceinline__ void gload_lds16(const void* g, void* l) {
    __builtin_amdgcn_global_load_lds(
        (const __attribute__((address_space(1))) unsigned int*)g,
        (__attribute__((address_space(3))) unsigned int*)l, 16, 0, 0);
}

// ---------------------------------------------------------------------------
// Fused pre-pass: flag scan + X->bf16 + W->bf16. 19.5us = 94% of its 119MB
// stream roofline. r12 lesson: do NOT move conversions into main.
// ---------------------------------------------------------------------------
__global__ __launch_bounds__(256) void prepass_kernel(
    const float* __restrict__ SPK, const float* __restrict__ X,
    const float* __restrict__ Wd,  const float* __restrict__ Wr,
    int* __restrict__ flags, short* __restrict__ X2,
    short* __restrict__ Wd2, short* __restrict__ Wr2)
{
    const int b   = blockIdx.x;      // 0..2047
    const int tid = threadIdx.x;

    {
        unsigned bits = 0;
        const f32x4* p = (const f32x4*)SPK + (size_t)b * 2048;
#pragma unroll
        for (int j = 0; j < 8; j++) {
            f32x4 v = p[tid + j * 256];
            bits |= __float_as_uint(v[0]) | __float_as_uint(v[1])
                  | __float_as_uint(v[2]) | __float_as_uint(v[3]);
        }
        if (__any(bits != 0) && (tid & 63) == 0)
            atomicOr(&flags[b >> 3], 1);
    }

    {
        const f32x4* src = (const f32x4*)X + (size_t)b * 1024;
        short4v*     dst = (short4v*)X2   + (size_t)b * 1024;
#pragma unroll
        for (int j = 0; j < 4; j++) {
            f32x4 v = src[tid + j * 256];
            dst[tid + j * 256] = (short4v){f2bf(v[0]), f2bf(v[1]),
                                           f2bf(v[2]), f2bf(v[3])};
        }
    }

    {
        int idx = b * 256 + tid;
        if (idx < 32768) {
            f32x4 v = ((const f32x4*)Wd)[idx];
            ((short4v*)Wd2)[idx] = (short4v){f2bf(v[0]), f2bf(v[1]),
                                             f2bf(v[2]), f2bf(v[3])};
        } else if (idx < 98304) {
            int k = idx - 32768;
            f32x4 v = ((const f32x4*)Wr)[k];
            ((short4v*)Wr2)[k] = (short4v){f2bf(v[0]), f2bf(v[1]),
                                           f2bf(v[2]), f2bf(v[3])};
        }
    }
}

// ---------------------------------------------------------------------------
// Main kernel (r10, BEST MEASURED: total 272.7us, main ~47us).
// global_load_lds-staged dense GEMM: 12 DMA/wave in flight (the proven
// Little's-law fix: depth lives in the DMA queue, not registers), K=256 in
// 2 serial chunks of 128, A 32KB + B 16KB = 48KB LDS (3 blocks/CU), sT
// epilogue overlay. Source-XOR swizzle (row&7)<<4 with linear LDS dest
// (involution; read applies same XOR) -> ~2 lanes/bank.
//
// Session ledger (why this exact shape):
//   depth:     6 reg-loads (77.7us) -> 12 DMA (47us) -> 6 DMA (~56us)
//   residency: 2/3/4 blocks per CU all tried; 3 best, never the lever
//   schedule:  serial == T3-pipelined (272.7 vs 274.9)
//   passes:    fused conversions >> f32-direct-in-main (272.7 vs 304.5)
//   stores:    nt == write-back
// ---------------------------------------------------------------------------
__global__ __launch_bounds__(256, 3) void spike_rnn_lif_kernel(
    const short* __restrict__ X2,   // bf16 [B, 256]
    const float* __restrict__ MEM,  // [B, 512]
    const float* __restrict__ SPK,  // [B, 512]
    const short* __restrict__ Wd2,  // bf16 [512, 256]
    const float* __restrict__ bd,   // [512]
    const short* __restrict__ Wr2,  // bf16 [512, 512]
    const float* __restrict__ br,   // [512]
    const float* __restrict__ tau,  // [512]
    const int*   __restrict__ flags,// [256]
    float* __restrict__ out)        // [2, B, 512]
{
    __shared__ __align__(16) char smem[49152];  // A[128][128]bf16 | B[64][128]bf16
    float* sT = (float*)smem;                    // epilogue overlay (17.4 KB)

    const int tid  = threadIdx.x;
    const int lane = tid & 63;
    const int w    = tid >> 6;
    const int wm   = w & 1;
    const int wn   = w >> 1;

    // XCD swizzle decode (bijective): L = ((bm/8)*8 + bn)*8 + bm%8
    const int L    = blockIdx.x;
    const int bm   = ((L >> 6) << 3) + (L & 7);
    const int bn   = (L >> 3) & 7;
    const int m0   = bm * BM;
    const int n0   = bn * BN;
    const int col  = lane & 15;
    const int quad = lane >> 4;

    const bool has_spk = (flags[bm] != 0);

    const int l16 = lane & 15, lr4 = lane >> 4;

    // Stage one K-chunk (c0 in {0,1}): A rows [m0,m0+128) cols [c0*128,+128),
    // B rows [n0,n0+64). Linear LDS dest, XOR-swizzled global source.
#define STAGE(c0)                                                             \
    do {                                                                      \
        _Pragma("unroll")                                                     \
        for (int i = 0; i < 8; i++) {                                         \
            int seg = w * 8 + i;               /* 1KB segment, 4 rows */      \
            int r   = seg * 4 + lr4;                                          \
            const char* src = (const char*)X2 + (size_t)(m0 + r) * 512        \
                            + (c0) * 256 + ((l16 * 16) ^ ((r & 7) << 4));     \
            gload_lds16(src, smem + seg * 1024);                              \
        }                                                                     \
        _Pragma("unroll")                                                     \
        for (int i = 0; i < 4; i++) {                                         \
            int seg = w * 4 + i;                                              \
            int r   = seg * 4 + lr4;                                          \
            const char* src = (const char*)Wd2 + (size_t)(n0 + r) * 512       \
                            + (c0) * 256 + ((l16 * 16) ^ ((r & 7) << 4));     \
            gload_lds16(src, smem + 32768 + seg * 1024);                      \
        }                                                                     \
    } while (0)

    // ---- Issue chunk-0 DMA first (owns the queue front), then MEM prefetch
    STAGE(0);

    const int c4   = tid & 15;
    const int ncol = n0 + c4 * 4;
    f32x4 mv0[4], mv1[4];
#pragma unroll
    for (int it = 0; it < 4; it++) {
        int r2 = (tid + it * 256) >> 4;
        mv0[it] = __builtin_nontemporal_load(
                      (const f32x4*)(MEM + (size_t)(m0 + r2) * DOUT + ncol));
        mv1[it] = __builtin_nontemporal_load(
                      (const f32x4*)(MEM + (size_t)(m0 + 64 + r2) * DOUT + ncol));
    }

    f32x4 acc[4][2];
#pragma unroll
    for (int i = 0; i < 4; i++)
#pragma unroll
        for (int j = 0; j < 2; j++)
            acc[i][j] = (f32x4){0.f, 0.f, 0.f, 0.f};

    const int swz  = (col & 7) << 4;   // row&7 == col&7 for all frag rows
    const int arow = wm * 64 + col;
    const int brow = wn * 32 + col;

#define DSLOAD(kk, aa, bb)                                                    \
    do {                                                                      \
        int ko = (quad * 16 + (kk) * 64) ^ swz;                               \
        _Pragma("unroll")                                                     \
        for (int t = 0; t < 4; t++)                                           \
            aa[t] = *(const short8*)(smem + (arow + t * 16) * 256 + ko);      \
        _Pragma("unroll")                                                     \
        for (int t = 0; t < 2; t++)                                           \
            bb[t] = *(const short8*)(smem + 32768 + (brow + t * 16) * 256 + ko); \
    } while (0)

#define MFMA_AB(aa, bb)                                                       \
    do {                                                                      \
        _Pragma("unroll")                                                     \
        for (int i = 0; i < 4; i++)                                           \
            _Pragma("unroll")                                                 \
            for (int j = 0; j < 2; j++)                                       \
                acc[i][j] = __builtin_amdgcn_mfma_f32_16x16x32_bf16(          \
                    aa[i], bb[j], acc[i][j], 0, 0, 0);                        \
    } while (0)

    short8 a0[4], b0[2], a1[4], b1[2];

    // ---- Chunk 0 ----
    __syncthreads();                       // drains DMA (and MEM prefetch)
    DSLOAD(0, a0, b0);
    DSLOAD(1, a1, b1); MFMA_AB(a0, b0);
    DSLOAD(2, a0, b0); MFMA_AB(a1, b1);
    DSLOAD(3, a1, b1); MFMA_AB(a0, b0);
    MFMA_AB(a1, b1);
    __syncthreads();                       // all waves done reading chunk 0

    // ---- Chunk 1 ----
    STAGE(1);
    __syncthreads();
    DSLOAD(0, a0, b0);
    DSLOAD(1, a1, b1); MFMA_AB(a0, b0);
    DSLOAD(2, a0, b0); MFMA_AB(a1, b1);
    DSLOAD(3, a1, b1); MFMA_AB(a0, b0);
    MFMA_AB(a1, b1);
#undef DSLOAD
#undef STAGE

    // ---- Phase 2: recurrent GEMM, K=512 — only when spikes exist ----
    if (has_spk) {
        const float* Abase = SPK + (size_t)(m0 + wm * 64 + col) * DOUT + quad * 8;
        const short* Bbase = Wr2 + (size_t)(n0 + wn * 32 + col) * DOUT + quad * 8;
#pragma unroll 4
        for (int ks = 0; ks < 16; ks++) {
            int k = ks * 32;
            short8 a[4], b[2];
#pragma unroll
            for (int t = 0; t < 4; t++) {
                const float* ap = Abase + (size_t)t * 16 * DOUT + k;
                f32x4 lo = *(const f32x4*)ap;
                f32x4 hi = *(const f32x4*)(ap + 4);
                a[t] = (short8){f2bf(lo[0]), f2bf(lo[1]), f2bf(lo[2]), f2bf(lo[3]),
                                f2bf(hi[0]), f2bf(hi[1]), f2bf(hi[2]), f2bf(hi[3])};
            }
#pragma unroll
            for (int t = 0; t < 2; t++)
                b[t] = *(const short8*)(Bbase + (size_t)t * 16 * DOUT + k);
            MFMA_AB(a, b);
        }
    }
#undef MFMA_AB

    float al[4], oma[4], bs[4];
#pragma unroll
    for (int q = 0; q < 4; q++) {
        al[q]  = expf(-1.0f / tau[ncol + q]);
        oma[q] = 1.0f - al[q];
        bs[q]  = bd[ncol + q] + br[ncol + q];
    }

    __syncthreads();   // protect sT overlay of staging LDS

#pragma unroll
    for (int c = 0; c < 2; c++) {
        if (c) __syncthreads();
        if (wm == c) {
            // C/D layout (verified): col = lane&15, row = quad*4 + reg
#pragma unroll
            for (int j = 0; j < 2; j++)
#pragma unroll
                for (int i = 0; i < 4; i++)
#pragma unroll
                    for (int rr = 0; rr < 4; rr++)
                        sT[(i * 16 + quad * 4 + rr) * 68 + wn * 32 + j * 16 + col]
                            = acc[i][j][rr];
        }
        __syncthreads();
#pragma unroll
        for (int it = 0; it < 4; it++) {
            int p   = tid + it * 256;
            int r2  = p >> 4;
            int row = m0 + c * 64 + r2;
            f32x4 d  = *(const f32x4*)(sT + r2 * 68 + c4 * 4);
            f32x4 mv = c ? mv1[it] : mv0[it];
            f32x4 sv = has_spk ? *(const f32x4*)(SPK + (size_t)row * DOUT + ncol)
                               : (f32x4){0.f, 0.f, 0.f, 0.f};
            f32x4 mn, sp;
#pragma unroll
            for (int q = 0; q < 4; q++) {
                mn[q] = mv[q] * al[q] + oma[q] * (d[q] + bs[q]) - 0.5f * sv[q];
                sp[q] = (mn[q] - 0.5f > 0.0f) ? 1.0f : 0.0f;
            }
            __builtin_nontemporal_store(mn,
                (f32x4*)(out + (size_t)row * DOUT + ncol));
            __builtin_nontemporal_store(sp,
                (f32x4*)(out + (size_t)BATCH * DOUT + (size_t)row * DOUT + ncol));
        }
    }
}

extern "C" void kernel_launch(void* const* d_in, const int* in_sizes, int n_in,
                              void* d_out, int out_size, void* d_ws, size_t ws_size,
                              hipStream_t stream) {
    const float* X   = (const float*)d_in[0];
    const float* MEM = (const float*)d_in[1];
    const float* SPK = (const float*)d_in[2];
    const float* Wd  = (const float*)d_in[3];
    const float* bd  = (const float*)d_in[4];
    const float* Wr  = (const float*)d_in[5];
    const float* br  = (const float*)d_in[6];
    const float* tau = (const float*)d_in[7];

    char*  ws    = (char*)d_ws;
    int*   flags = (int*)  (ws + WS_FLAGS);
    short* Wd2   = (short*)(ws + WS_WD2);
    short* Wr2   = (short*)(ws + WS_WR2);
    short* X2    = (short*)(ws + WS_X2);

    hipMemsetAsync(flags, 0, 256 * sizeof(int), stream);   // graph-capture-safe
    prepass_kernel<<<2048, 256, 0, stream>>>(SPK, X, Wd, Wr, flags, X2, Wd2, Wr2);

    spike_rnn_lif_kernel<<<2048, 256, 0, stream>>>(X2, MEM, SPK, Wd2, bd, Wr2, br,
                                                   tau, flags, (float*)d_out);
}